// Round 1
// baseline (609.011 us; speedup 1.0000x reference)
//
#include <hip/hip_runtime.h>
#include <cstdint>

#define N_NODES 50000
#define N_EDGES 800000
#define D 96
#define NEG_SLOPE 0.2f

// ---- monotonic float<->uint encoding for atomicMax on signed floats ----
__device__ __forceinline__ unsigned enc_f32(float f) {
    unsigned b = __float_as_uint(f);
    return (b & 0x80000000u) ? ~b : (b | 0x80000000u);
}
__device__ __forceinline__ float dec_f32(unsigned u) {
    return __uint_as_float((u & 0x80000000u) ? (u ^ 0x80000000u) : ~u);
}

// K0: transpose W [D,D] -> Wt [D,D] so Wt[c][k] = W[k][c]
__global__ void k0_transpose(const float* __restrict__ W, float* __restrict__ Wt) {
    int idx = blockIdx.x * blockDim.x + threadIdx.x;
    if (idx < D * D) {
        int k = idx / D, c = idx % D;
        Wt[c * D + k] = W[k * D + c];
    }
}

// K1: one block per row. h[row] = x[row] @ W, a_src[row] = h.att_src,
// a_dst[row] = h.att_dst, m_enc[row] = enc(leaky_relu(a_src+a_dst))  (self-loop init)
__global__ __launch_bounds__(96) void k1_gemm_att(
    const float* __restrict__ x, const float* __restrict__ Wt,
    const float* __restrict__ att_src, const float* __restrict__ att_dst,
    float* __restrict__ h, float* __restrict__ a_src, float* __restrict__ a_dst,
    unsigned* __restrict__ m_enc) {
    __shared__ float xs[D];
    __shared__ float ra[D], rb[D];
    const int row = blockIdx.x;
    const int tid = threadIdx.x;
    xs[tid] = x[row * D + tid];
    __syncthreads();
    float val = 0.f;
    const float* wrow = Wt + tid * D;
#pragma unroll
    for (int k = 0; k < D; k += 4) {
        float4 xv = *reinterpret_cast<const float4*>(&xs[k]);
        float4 wv = *reinterpret_cast<const float4*>(&wrow[k]);
        val += xv.x * wv.x + xv.y * wv.y + xv.z * wv.z + xv.w * wv.w;
    }
    h[row * D + tid] = val;
    ra[tid] = val * att_src[tid];
    rb[tid] = val * att_dst[tid];
    __syncthreads();
    for (int s = 48; s >= 3; s >>= 1) {
        if (tid < s) { ra[tid] += ra[tid + s]; rb[tid] += rb[tid + s]; }
        __syncthreads();
    }
    if (tid == 0) {
        float as = ra[0] + ra[1] + ra[2];
        float ad = rb[0] + rb[1] + rb[2];
        a_src[row] = as;
        a_dst[row] = ad;
        float e = as + ad;
        e = e > 0.f ? e : NEG_SLOPE * e;
        m_enc[row] = enc_f32(e);
    }
}

// K2: per-edge logit + segment max via atomicMax on encoded uint
__global__ void k2_edge_max(const int* __restrict__ ei, const float* __restrict__ a_src,
                            const float* __restrict__ a_dst, float* __restrict__ e_vals,
                            unsigned* __restrict__ m_enc) {
    int e = blockIdx.x * blockDim.x + threadIdx.x;
    if (e >= N_EDGES) return;
    int s = ei[e], d = ei[N_EDGES + e];
    float v = a_src[s] + a_dst[d];
    v = v > 0.f ? v : NEG_SLOPE * v;
    e_vals[e] = v;
    atomicMax(&m_enc[d], enc_f32(v));
}

// K3: init accumulators with the self-loop contribution (unnormalized)
__global__ void k3_init(const float* __restrict__ h, const float* __restrict__ a_src,
                        const float* __restrict__ a_dst, const unsigned* __restrict__ m_enc,
                        float* __restrict__ denom, float* __restrict__ out) {
    int i = blockIdx.x * blockDim.y + threadIdx.y;
    if (i >= N_NODES) return;
    int d = threadIdx.x;
    float m = dec_f32(m_enc[i]);
    float e = a_src[i] + a_dst[i];
    e = e > 0.f ? e : NEG_SLOPE * e;
    float w = __expf(e - m);
    if (d == 0) denom[i] = w;
    out[i * D + d] = h[i * D + d] * w;
}

// K4: per-edge weighted scatter (unnormalized) + denom accumulation
__global__ void k4_scatter(const int* __restrict__ ei, const float* __restrict__ e_vals,
                           const unsigned* __restrict__ m_enc, const float* __restrict__ h,
                           float* __restrict__ denom, float* __restrict__ out) {
    int e = blockIdx.x * blockDim.y + threadIdx.y;
    if (e >= N_EDGES) return;
    int d = threadIdx.x;
    int s = ei[e], dd = ei[N_EDGES + e];
    float w = __expf(e_vals[e] - dec_f32(m_enc[dd]));
    if (d == 0) atomicAdd(&denom[dd], w);
    atomicAdd(&out[dd * D + d], h[s * D + d] * w);
}

// K5: normalize + bias + tanh (in place on d_out)
__global__ void k5_final(const float* __restrict__ denom, const float* __restrict__ bias,
                         float* __restrict__ out) {
    int i = blockIdx.x * blockDim.y + threadIdx.y;
    if (i >= N_NODES) return;
    int d = threadIdx.x;
    float v = out[i * D + d] / (denom[i] + 1e-16f) + bias[d];
    out[i * D + d] = tanhf(v);
}

extern "C" void kernel_launch(void* const* d_in, const int* in_sizes, int n_in,
                              void* d_out, int out_size, void* d_ws, size_t ws_size,
                              hipStream_t stream) {
    const float* x       = (const float*)d_in[0];
    const float* W       = (const float*)d_in[1];
    const float* att_src = (const float*)d_in[2];
    const float* att_dst = (const float*)d_in[3];
    const float* bias    = (const float*)d_in[4];
    const int*   ei      = (const int*)d_in[5];
    float* out = (float*)d_out;

    char* ws = (char*)d_ws;
    float*    Wt     = (float*)ws;    ws += (size_t)D * D * 4;
    float*    h      = (float*)ws;    ws += (size_t)N_NODES * D * 4;
    float*    a_src  = (float*)ws;    ws += (size_t)N_NODES * 4;
    float*    a_dst  = (float*)ws;    ws += (size_t)N_NODES * 4;
    unsigned* m_enc  = (unsigned*)ws; ws += (size_t)N_NODES * 4;
    float*    denom  = (float*)ws;    ws += (size_t)N_NODES * 4;
    float*    e_vals = (float*)ws;    ws += (size_t)N_EDGES * 4;

    k0_transpose<<<(D * D + 255) / 256, 256, 0, stream>>>(W, Wt);
    k1_gemm_att<<<N_NODES, 96, 0, stream>>>(x, Wt, att_src, att_dst, h, a_src, a_dst, m_enc);
    k2_edge_max<<<(N_EDGES + 255) / 256, 256, 0, stream>>>(ei, a_src, a_dst, e_vals, m_enc);
    k3_init<<<(N_NODES + 3) / 4, dim3(96, 4), 0, stream>>>(h, a_src, a_dst, m_enc, denom, out);
    k4_scatter<<<(N_EDGES + 1) / 2, dim3(96, 2), 0, stream>>>(ei, e_vals, m_enc, h, denom, out);
    k5_final<<<(N_NODES + 3) / 4, dim3(96, 4), 0, stream>>>(denom, bias, out);
}

// Round 2
// 500.638 us; speedup vs baseline: 1.2165x; 1.2165x over previous
//
#include <hip/hip_runtime.h>
#include <cstdint>

#define N_NODES 50000
#define N_EDGES 800000
#define D 96
#define NEG_SLOPE 0.2f
#define SCAN_THREADS 1024

// K0: transpose W [D,D] -> Wt [D,D] so Wt[c][k] = W[k][c]
__global__ void k0_transpose(const float* __restrict__ W, float* __restrict__ Wt) {
    int idx = blockIdx.x * blockDim.x + threadIdx.x;
    if (idx < D * D) {
        int k = idx / D, c = idx % D;
        Wt[c * D + k] = W[k * D + c];
    }
}

// K1: 4 rows per block. h[row] = x[row] @ W, a_src[row] = h.att_src, a_dst[row] = h.att_dst
__global__ __launch_bounds__(384) void k1_gemm_att(
    const float* __restrict__ x, const float* __restrict__ Wt,
    const float* __restrict__ att_src, const float* __restrict__ att_dst,
    float* __restrict__ h, float* __restrict__ a_src, float* __restrict__ a_dst) {
    __shared__ float xs[4][D];
    __shared__ float ra[4][D], rb[4][D];
    const int r = threadIdx.y;               // 0..3
    const int tid = threadIdx.x;             // 0..95
    const int row = blockIdx.x * 4 + r;
    if (row < N_NODES) xs[r][tid] = x[(size_t)row * D + tid];
    __syncthreads();
    float val = 0.f;
    const float* wrow = Wt + tid * D;
#pragma unroll
    for (int k = 0; k < D; k += 4) {
        float4 xv = *reinterpret_cast<const float4*>(&xs[r][k]);
        float4 wv = *reinterpret_cast<const float4*>(&wrow[k]);
        val += xv.x * wv.x + xv.y * wv.y + xv.z * wv.z + xv.w * wv.w;
    }
    ra[r][tid] = val * att_src[tid];
    rb[r][tid] = val * att_dst[tid];
    __syncthreads();
    for (int s = 48; s >= 3; s >>= 1) {
        if (tid < s) { ra[r][tid] += ra[r][tid + s]; rb[r][tid] += rb[r][tid + s]; }
        __syncthreads();
    }
    if (row < N_NODES) {
        h[(size_t)row * D + tid] = val;
        if (tid == 0) {
            a_src[row] = ra[r][0] + ra[r][1] + ra[r][2];
            a_dst[row] = rb[r][0] + rb[r][1] + rb[r][2];
        }
    }
}

// zero the histogram
__global__ void k_zero(int* __restrict__ p, int n) {
    int i = blockIdx.x * blockDim.x + threadIdx.x;
    if (i < n) p[i] = 0;
}

// histogram of destinations
__global__ void k_hist(const int* __restrict__ ei, int* __restrict__ ptr) {
    int e = blockIdx.x * blockDim.x + threadIdx.x;
    if (e < N_EDGES) atomicAdd(&ptr[ei[N_EDGES + e]], 1);
}

// single-block in-place exclusive scan of ptr[N_NODES]
__global__ __launch_bounds__(SCAN_THREADS) void k_scan(int* __restrict__ ptr) {
    __shared__ int part[SCAN_THREADS];
    const int CHUNK = (N_NODES + SCAN_THREADS - 1) / SCAN_THREADS;
    const int t = threadIdx.x;
    const int lo = t * CHUNK;
    const int hi = min(lo + CHUNK, N_NODES);
    int s = 0;
    for (int i = lo; i < hi; ++i) s += ptr[i];
    part[t] = s;
    __syncthreads();
    for (int off = 1; off < SCAN_THREADS; off <<= 1) {
        int v = (t >= off) ? part[t - off] : 0;
        __syncthreads();
        part[t] += v;
        __syncthreads();
    }
    int run = (t == 0) ? 0 : part[t - 1];
    for (int i = lo; i < hi; ++i) {
        int c = ptr[i];
        ptr[i] = run;
        run += c;
    }
}

// scatter edge sources into dst-sorted order; ptr[d] advances from start to end
__global__ void k_scatter_idx(const int* __restrict__ ei, int* __restrict__ ptr,
                              int* __restrict__ src_sorted) {
    int e = blockIdx.x * blockDim.x + threadIdx.x;
    if (e >= N_EDGES) return;
    int s = ei[e], d = ei[N_EDGES + e];
    int pos = atomicAdd(&ptr[d], 1);
    src_sorted[pos] = s;
}

// one block (96 threads) per node: segment max, weighted gather, normalize+bias+tanh
__global__ __launch_bounds__(96) void k_gather(
    const int* __restrict__ ptr, const int* __restrict__ src_sorted,
    const float* __restrict__ a_src, const float* __restrict__ a_dst,
    const float* __restrict__ h, const float* __restrict__ bias,
    float* __restrict__ out) {
    const int i = blockIdx.x;
    const int t = threadIdx.x;
    const int start = (i == 0) ? 0 : ptr[i - 1];  // ptr holds segment ends after scatter
    const int end = ptr[i];
    const float adst = a_dst[i];
    float e_self = a_src[i] + adst;
    e_self = e_self > 0.f ? e_self : NEG_SLOPE * e_self;
    // pass 1: segment max (broadcast loads, redundant across threads)
    float m = e_self;
    for (int k = start; k < end; ++k) {
        float v = a_src[src_sorted[k]] + adst;
        v = v > 0.f ? v : NEG_SLOPE * v;
        m = fmaxf(m, v);
    }
    // pass 2: weighted accumulate
    float wsum = __expf(e_self - m);
    float acc = h[(size_t)i * D + t] * wsum;
    for (int k = start; k < end; ++k) {
        int s = src_sorted[k];
        float v = a_src[s] + adst;
        v = v > 0.f ? v : NEG_SLOPE * v;
        float w = __expf(v - m);
        wsum += w;
        acc += h[(size_t)s * D + t] * w;
    }
    out[(size_t)i * D + t] = tanhf(acc / (wsum + 1e-16f) + bias[t]);
}

extern "C" void kernel_launch(void* const* d_in, const int* in_sizes, int n_in,
                              void* d_out, int out_size, void* d_ws, size_t ws_size,
                              hipStream_t stream) {
    const float* x       = (const float*)d_in[0];
    const float* W       = (const float*)d_in[1];
    const float* att_src = (const float*)d_in[2];
    const float* att_dst = (const float*)d_in[3];
    const float* bias    = (const float*)d_in[4];
    const int*   ei      = (const int*)d_in[5];
    float* out = (float*)d_out;

    char* ws = (char*)d_ws;
    float* Wt         = (float*)ws; ws += (size_t)D * D * 4;
    float* h          = (float*)ws; ws += (size_t)N_NODES * D * 4;
    float* a_src      = (float*)ws; ws += (size_t)N_NODES * 4;
    float* a_dst      = (float*)ws; ws += (size_t)N_NODES * 4;
    int*   ptr        = (int*)ws;   ws += (size_t)N_NODES * 4;
    int*   src_sorted = (int*)ws;   ws += (size_t)N_EDGES * 4;

    k0_transpose<<<(D * D + 255) / 256, 256, 0, stream>>>(W, Wt);
    k_zero<<<(N_NODES + 255) / 256, 256, 0, stream>>>(ptr, N_NODES);
    k_hist<<<(N_EDGES + 255) / 256, 256, 0, stream>>>(ei, ptr);
    k1_gemm_att<<<(N_NODES + 3) / 4, dim3(96, 4), 0, stream>>>(x, Wt, att_src, att_dst, h, a_src, a_dst);
    k_scan<<<1, SCAN_THREADS, 0, stream>>>(ptr);
    k_scatter_idx<<<(N_EDGES + 255) / 256, 256, 0, stream>>>(ei, ptr, src_sorted);
    k_gather<<<N_NODES, 96, 0, stream>>>(ptr, src_sorted, a_src, a_dst, h, bias, out);
}